// Round 1
// baseline (4910.386 us; speedup 1.0000x reference)
//
#include <hip/hip_runtime.h>
#include <hip/hip_bf16.h>
#include <math.h>

// Problem constants
#define TSTEPS 128
#define BATCH  64
#define NTOK   10000
#define NBK    6
#define BSZ    100
#define NHID   600

// Workspace layout (float offsets). Total ~11.12M floats = 44.5 MB.
#define OFF_S1   0ull                          // 8192*600  : s1[t,b,n*100+d] = (Wq_n · k1)/sqrt(128)
#define OFF_U    (OFF_S1 + 8192ull*600)        // 8192*100  : u[t,b,j] = v1 @ fc_w^T
#define OFF_WQT  (OFF_U + 8192ull*100)         // 6*128*100 : inp_wq transposed+scaled
#define OFF_FCT  (OFF_WQT + 76800ull)          // 128*100   : inp_fc_w transposed
#define OFF_WIHT (OFF_FCT + 12800ull)          // 6*100*300 : gru_w_ih transposed [n][d][g]
#define OFF_WHHT (OFF_WIHT + 180000ull)        // 6*100*300
#define OFF_MFCT (OFF_WHHT + 180000ull)        // 64*100    : mha_fc_w transposed
#define OFF_MGT  (OFF_MFCT + 6400ull)          // 64*100    : mha_gate_w transposed
#define OFF_OUT  (OFF_MGT + 6400ull)           // 8192*600  : per-step hidden states

// ---------------------------------------------------------------------------
// Kernel 1: one-time weight transposes (coalesced layouts for the scan)
// ---------------------------------------------------------------------------
__global__ __launch_bounds__(256) void transpose_kernel(
    const float* __restrict__ inp_wq, const float* __restrict__ inp_fc_w,
    const float* __restrict__ gru_w_ih, const float* __restrict__ gru_w_hh,
    const float* __restrict__ mha_fc_w, const float* __restrict__ mha_gate_w,
    float* __restrict__ ws)
{
    const float rs = 0.08838834764831845f; // 1/sqrt(128) folded into wqT
    int total = 76800 + 12800 + 180000 + 180000 + 6400 + 6400;
    for (int idx = blockIdx.x * 256 + threadIdx.x; idx < total; idx += gridDim.x * 256) {
        int i = idx;
        if (i < 76800) {                       // wqT[n][i][d] = wq[n][d][i] * rs
            int n = i / 12800, r = i % 12800, ii = r / 100, d = r % 100;
            ws[OFF_WQT + i] = inp_wq[n * 12800 + d * 128 + ii] * rs;
        } else if ((i -= 76800) < 12800) {     // fcT[i][j] = fc_w[j][i]
            int ii = i / 100, j = i % 100;
            ws[OFF_FCT + i] = inp_fc_w[j * 128 + ii];
        } else if ((i -= 12800) < 180000) {    // wihT[n][d][g] = w_ih[n][g][d]
            int n = i / 30000, r = i % 30000, d = r / 300, g = r % 300;
            ws[OFF_WIHT + i] = gru_w_ih[n * 30000 + g * 100 + d];
        } else if ((i -= 180000) < 180000) {
            int n = i / 30000, r = i % 30000, d = r / 300, g = r % 300;
            ws[OFF_WHHT + i] = gru_w_hh[n * 30000 + g * 100 + d];
        } else if ((i -= 180000) < 6400) {     // mfcT[e][j] = mha_fc_w[j][e]
            int e = i / 100, j = i % 100;
            ws[OFF_MFCT + i] = mha_fc_w[j * 64 + e];
        } else {
            i -= 6400;
            int e = i / 100, j = i % 100;
            ws[OFF_MGT + i] = mha_gate_w[j * 64 + e];
        }
    }
}

// ---------------------------------------------------------------------------
// Kernel 2: precompute, fully parallel over (t,b):
//   k1 = emb @ Wk[0];  v1 = emb @ Wv[0];  u = v1 @ fc_w^T;
//   s1[n,d] = (Wq[n] · k1)[d] / sqrt(128)
// 16 rows per workgroup to amortize weight streaming.
// ---------------------------------------------------------------------------
__global__ __launch_bounds__(256) void precompute_kernel(
    const int* __restrict__ input, const float* __restrict__ encoder_w,
    const float* __restrict__ inp_wk, const float* __restrict__ inp_wv,
    float* __restrict__ ws)
{
    __shared__ float es[16 * 600];
    __shared__ float k1s[16 * 128];
    __shared__ float v1s[16 * 128];
    __shared__ int   toks[16];
    int tid = threadIdx.x;
    int row0 = blockIdx.x * 16;              // flat row = t*64 + b
    if (tid < 16) toks[tid] = input[row0 + tid];
    __syncthreads();
    for (int i = tid; i < 16 * 600; i += 256) {
        int r = i / 600, d = i % 600;
        es[i] = encoder_w[(size_t)toks[r] * 600 + d];
    }
    __syncthreads();
    {
        int mat = tid >> 7, ii = tid & 127;
        const float* W = (mat == 0 ? inp_wk : inp_wv); // slice 0 of (2,600,128)
        float acc[16];
#pragma unroll
        for (int r = 0; r < 16; r++) acc[r] = 0.f;
        for (int d = 0; d < 600; d++) {
            float wv = W[d * 128 + ii];      // coalesced
#pragma unroll
            for (int r = 0; r < 16; r++) acc[r] += es[r * 600 + d] * wv; // LDS broadcast
        }
        float* dst = (mat == 0 ? k1s : v1s);
#pragma unroll
        for (int r = 0; r < 16; r++) dst[r * 128 + ii] = acc[r];
    }
    __syncthreads();
    const float* fcT = ws + OFF_FCT;
    for (int i = tid; i < 16 * 100; i += 256) {
        int r = i / 100, j = i % 100;
        float acc = 0.f;
        for (int e = 0; e < 128; e++) acc += v1s[r * 128 + e] * fcT[e * 100 + j];
        ws[OFF_U + (size_t)(row0 + r) * 100 + j] = acc;
    }
    const float* wqT = ws + OFF_WQT;
    for (int i = tid; i < 16 * 600; i += 256) {
        int r = i / 600, q = i % 600, n = q / 100, d = q % 100;
        float acc = 0.f;
        for (int e = 0; e < 128; e++) acc += k1s[r * 128 + e] * wqT[(n * 128 + e) * 100 + d];
        ws[OFF_S1 + (size_t)(row0 + r) * 600 + q] = acc;
    }
}

// ---------------------------------------------------------------------------
// Kernel 3: the sequential scan. One workgroup per batch element (the
// recurrence is independent per batch -> no grid sync). 512 threads.
// Weights streamed from L2 each step; gh cached per block when unmasked.
// ---------------------------------------------------------------------------
__global__ __launch_bounds__(512) void scan_kernel(
    const float* __restrict__ hidden, const float* __restrict__ inp_fc_b,
    const float* __restrict__ mha_wq, const float* __restrict__ mha_wk,
    const float* __restrict__ mha_wv, const float* __restrict__ mha_fc_b,
    const float* __restrict__ mha_gate_b, const float* __restrict__ gru_b_ih,
    const float* __restrict__ gru_b_hh, float* __restrict__ ws)
{
    __shared__ float hx[600], iu[600], gxs[1800], ghs[1800], hns[600];
    __shared__ float qkv[1152], att[144], outv[384];
    __shared__ float a0s[6], msk[6], mprev[6];

    int b = blockIdx.x, tid = threadIdx.x;
    const float* s1  = ws + OFF_S1;
    const float* uu  = ws + OFF_U;
    const float* wih = ws + OFF_WIHT;
    const float* whh = ws + OFF_WHHT;
    const float* mfcT = ws + OFF_MFCT;
    const float* mgT  = ws + OFF_MGT;
    float* outp = ws + OFF_OUT;

    for (int d = tid; d < 600; d += 512) hx[d] = hidden[b * 600 + d];
    if (tid < 6) mprev[tid] = 1.f;
    __syncthreads();

    for (int t = 0; t < TSTEPS; t++) {
        const float* s1t = s1 + (size_t)(t * 64 + b) * 600;
        const float* ut  = uu + (size_t)(t * 64 + b) * 100;

        // ---- scores: a0[n] = sigmoid(hx_n · s1_n)   (scale folded in s1)
        int wave = tid >> 6, lane = tid & 63;
        if (wave < 6) {
            float p = hx[wave * 100 + lane] * s1t[wave * 100 + lane];
            if (lane < 36) p += hx[wave * 100 + 64 + lane] * s1t[wave * 100 + 64 + lane];
#pragma unroll
            for (int off = 32; off > 0; off >>= 1) p += __shfl_down(p, off, 64);
            if (lane == 0) a0s[wave] = 1.f / (1.f + expf(-p));
        }
        __syncthreads();

        // ---- top-k(4 of 6) mask (thread 0) + inp_use = a0*u + fc_b (all)
        if (tid == 0) {
            float s[6];
            for (int n = 0; n < 6; n++) s[n] = a0s[n];
            for (int a = 0; a < 5; a++)
                for (int c = a + 1; c < 6; c++)
                    if (s[c] > s[a]) { float tmp = s[a]; s[a] = s[c]; s[c] = tmp; }
            float kth = s[3] - 0.01f;
            for (int n = 0; n < 6; n++) msk[n] = (a0s[n] > kth) ? 1.f : 0.f;
        }
        for (int i = tid; i < 600; i += 512) {
            int n = i / 100, j = i % 100;
            iu[i] = a0s[n] * ut[j] + inp_fc_b[j];
        }
        __syncthreads();

        // ---- BlockGRU gates (gh cached when block n was not updated last step)
        for (int i = tid; i < 1800; i += 512) {
            int n = i / 300, g = i % 300;
            const float* wi = wih + n * 30000 + g;
            const float* xv = iu + n * 100;
            float ax = gru_b_ih[n * 300 + g];
            if (mprev[n] != 0.f) {
                const float* wh = whh + n * 30000 + g;
                const float* hv = hx + n * 100;
                float ah = gru_b_hh[n * 300 + g];
                for (int d = 0; d < 100; d++) {
                    ax += xv[d] * wi[d * 300];
                    ah += hv[d] * wh[d * 300];
                }
                ghs[i] = ah;
            } else {
                for (int d = 0; d < 100; d++) ax += xv[d] * wi[d * 300];
            }
            gxs[i] = ax;
        }
        __syncthreads();

        // ---- GRU combine (PyTorch gate order r,z,n)
        for (int i = tid; i < 600; i += 512) {
            int n = i / 100, j = i % 100;
            float r  = 1.f / (1.f + expf(-(gxs[n*300 + j]       + ghs[n*300 + j])));
            float z  = 1.f / (1.f + expf(-(gxs[n*300 + 100 + j] + ghs[n*300 + 100 + j])));
            float nn = tanhf(gxs[n*300 + 200 + j] + r * ghs[n*300 + 200 + j]);
            hns[i] = (1.f - z) * nn + z * hx[i];
        }
        __syncthreads();

        // ---- MHA q/k/v projections (per-block weights, e coalesced)
        for (int i = tid; i < 1152; i += 512) {
            int mat = i / 384, rem = i % 384, n = rem / 64, e = rem % 64;
            const float* W = (mat == 0 ? mha_wq : (mat == 1 ? mha_wk : mha_wv));
            const float* hv = hns + n * 100;
            const float* wp = W + n * 6400 + e;
            float acc = 0.f;
            for (int d = 0; d < 100; d++) acc += hv[d] * wp[d * 64];
            qkv[i] = acc;
        }
        __syncthreads();

        // ---- attention logits (4 heads x 6 q x 6 k), scale 1/sqrt(16)
        if (tid < 144) {
            int h = tid / 36, rem = tid % 36, nq = rem / 6, nk = rem % 6;
            const float* qp = qkv + nq * 64 + h * 16;
            const float* kp = qkv + 384 + nk * 64 + h * 16;
            float acc = 0.f;
#pragma unroll
            for (int d = 0; d < 16; d++) acc += qp[d] * kp[d];
            att[tid] = acc * 0.25f;
        }
        __syncthreads();
        if (tid < 24) {          // softmax rows (h,nq)
            int base = tid * 6;
            float m = att[base];
            for (int k2 = 1; k2 < 6; k2++) m = fmaxf(m, att[base + k2]);
            float s = 0.f, ex[6];
            for (int k2 = 0; k2 < 6; k2++) { ex[k2] = expf(att[base + k2] - m); s += ex[k2]; }
            float inv = 1.f / s;
            for (int k2 = 0; k2 < 6; k2++) att[base + k2] = ex[k2] * inv;
        }
        __syncthreads();

        // ---- attn @ V
        for (int i = tid; i < 384; i += 512) {
            int n = i / 64, e = i % 64, h = e / 16;
            const float* ap = att + h * 36 + n * 6;
            float acc = 0.f;
#pragma unroll
            for (int nk = 0; nk < 6; nk++) acc += ap[nk] * qkv[768 + nk * 64 + e];
            outv[i] = acc;
        }
        __syncthreads();

        // ---- fc/gate projection (only for masked blocks) + hx update + store
        float* og = outp + (size_t)(t * 64 + b) * 600;
        for (int i = tid; i < 600; i += 512) {
            int n = i / 100, j = i % 100;
            float newv;
            if (msk[n] != 0.f) {
                float pj = mha_fc_b[j], gt = mha_gate_b[j];
                const float* ov = outv + n * 64;
                for (int e = 0; e < 64; e++) {
                    float o = ov[e];
                    pj += o * mfcT[e * 100 + j];
                    gt += o * mgT[e * 100 + j];
                }
                newv = (1.f / (1.f + expf(-gt))) * tanhf(pj);
            } else {
                newv = hx[i];
            }
            hx[i] = newv;        // each thread touches only its own i
            og[i] = newv;
        }
        __syncthreads();
        if (tid < 6) mprev[tid] = msk[tid];
        __syncthreads();
    }
}

// ---------------------------------------------------------------------------
// Kernel 4: decode GEMM  C(8192x10000) = A(8192x600) @ W^T + b   (fp32)
// 128x128 tile, 256 threads, 8x8 per thread, K-chunk 8.
// ---------------------------------------------------------------------------
__global__ __launch_bounds__(256) void decode_kernel(
    const float* __restrict__ A, const float* __restrict__ W,
    const float* __restrict__ bias, float* __restrict__ C)
{
    __shared__ float As[8][132];
    __shared__ float Bs[8][132];
    int tid = threadIdx.x;
    int m0 = blockIdx.x * 128;
    int n0 = blockIdx.y * 128;
    int tn = tid % 16, tm = tid / 16;
    int lr = tid / 2, lc = tid % 2;

    float acc[8][8];
#pragma unroll
    for (int i = 0; i < 8; i++)
#pragma unroll
        for (int j = 0; j < 8; j++) acc[i][j] = 0.f;

    for (int k0 = 0; k0 < 600; k0 += 8) {
        float4 av = *(const float4*)(A + (size_t)(m0 + lr) * 600 + k0 + lc * 4);
        float4 bv = make_float4(0.f, 0.f, 0.f, 0.f);
        int wrow = n0 + lr;
        if (wrow < NTOK) bv = *(const float4*)(W + (size_t)wrow * 600 + k0 + lc * 4);
        __syncthreads();
        As[lc*4+0][lr] = av.x; As[lc*4+1][lr] = av.y; As[lc*4+2][lr] = av.z; As[lc*4+3][lr] = av.w;
        Bs[lc*4+0][lr] = bv.x; Bs[lc*4+1][lr] = bv.y; Bs[lc*4+2][lr] = bv.z; Bs[lc*4+3][lr] = bv.w;
        __syncthreads();
#pragma unroll
        for (int kk = 0; kk < 8; kk++) {
            float4 x0 = *(const float4*)&As[kk][tm * 8];
            float4 x1 = *(const float4*)&As[kk][tm * 8 + 4];
            float4 y0 = *(const float4*)&Bs[kk][tn * 8];
            float4 y1 = *(const float4*)&Bs[kk][tn * 8 + 4];
            float a8[8] = {x0.x, x0.y, x0.z, x0.w, x1.x, x1.y, x1.z, x1.w};
            float b8[8] = {y0.x, y0.y, y0.z, y0.w, y1.x, y1.y, y1.z, y1.w};
#pragma unroll
            for (int i = 0; i < 8; i++)
#pragma unroll
                for (int j = 0; j < 8; j++) acc[i][j] += a8[i] * b8[j];
        }
    }

    int nbase = n0 + tn * 8;
    if (nbase < NTOK) {          // NTOK % 8 == 0 -> whole 8-col group valid or none
        float4 bb0 = *(const float4*)(bias + nbase);
        float4 bb1 = *(const float4*)(bias + nbase + 4);
#pragma unroll
        for (int i = 0; i < 8; i++) {
            float* crow = C + (size_t)(m0 + tm * 8 + i) * NTOK + nbase;
            float4 s0 = make_float4(acc[i][0]+bb0.x, acc[i][1]+bb0.y, acc[i][2]+bb0.z, acc[i][3]+bb0.w);
            float4 s1v = make_float4(acc[i][4]+bb1.x, acc[i][5]+bb1.y, acc[i][6]+bb1.z, acc[i][7]+bb1.w);
            *(float4*)crow = s0;
            *(float4*)(crow + 4) = s1v;
        }
    }
}

// ---------------------------------------------------------------------------
// Kernel 5: hx_final tail + scalar
// ---------------------------------------------------------------------------
__global__ __launch_bounds__(256) void finalize_kernel(
    const float* __restrict__ outp, float* __restrict__ out)
{
    int idx = blockIdx.x * 256 + threadIdx.x;
    if (idx < 38400) out[81920000u + idx] = outp[(size_t)(127 * 64) * 600 + idx];
    if (idx == 38400) out[81958400u] = 0.0f;
}

// ---------------------------------------------------------------------------
extern "C" void kernel_launch(void* const* d_in, const int* in_sizes, int n_in,
                              void* d_out, int out_size, void* d_ws, size_t ws_size,
                              hipStream_t stream)
{
    const int*   input      = (const int*)  d_in[0];
    const float* hidden     = (const float*)d_in[1];
    const float* encoder_w  = (const float*)d_in[2];
    const float* inp_wq     = (const float*)d_in[3];
    const float* inp_wk     = (const float*)d_in[4];
    const float* inp_wv     = (const float*)d_in[5];
    const float* inp_fc_w   = (const float*)d_in[6];
    const float* inp_fc_b   = (const float*)d_in[7];
    const float* mha_wq     = (const float*)d_in[8];
    const float* mha_wk     = (const float*)d_in[9];
    const float* mha_wv     = (const float*)d_in[10];
    const float* mha_fc_w   = (const float*)d_in[11];
    const float* mha_fc_b   = (const float*)d_in[12];
    const float* mha_gate_w = (const float*)d_in[13];
    const float* mha_gate_b = (const float*)d_in[14];
    const float* gru_w_ih   = (const float*)d_in[15];
    const float* gru_w_hh   = (const float*)d_in[16];
    const float* gru_b_ih   = (const float*)d_in[17];
    const float* gru_b_hh   = (const float*)d_in[18];
    const float* dec_w      = (const float*)d_in[19];
    const float* dec_b      = (const float*)d_in[20];
    float* out = (float*)d_out;
    float* ws  = (float*)d_ws;   // needs ~44.5 MB

    transpose_kernel<<<256, 256, 0, stream>>>(inp_wq, inp_fc_w, gru_w_ih, gru_w_hh,
                                              mha_fc_w, mha_gate_w, ws);
    precompute_kernel<<<512, 256, 0, stream>>>(input, encoder_w, inp_wk, inp_wv, ws);
    scan_kernel<<<64, 512, 0, stream>>>(hidden, inp_fc_b, mha_wq, mha_wk, mha_wv,
                                        mha_fc_b, mha_gate_b, gru_b_ih, gru_b_hh, ws);
    decode_kernel<<<dim3(64, 79), dim3(256), 0, stream>>>(ws + OFF_OUT, dec_w, dec_b, out);
    finalize_kernel<<<151, 256, 0, stream>>>(ws + OFF_OUT, out);
}